// Round 2
// baseline (417.991 us; speedup 1.0000x reference)
//
#include <hip/hip_runtime.h>
#include <stdint.h>

#define T_LEN 8192
#define C_LEN 64
#define OUT_LEN 8

// Kernel A: per row (b,t): pred = argmax_c x[b,t,c] (ties -> lowest c),
// conf = 1 / sum_c exp(x[b,t,c] - max_c) == max of softmax.
// 16 lanes/row, float4 per lane (1 KB per wave, coalesced).
// Argmax reduced via packed u64 key (sign-corrected float bits | ~idx):
// one u64 shuffle per step instead of 2 shuffles + 8 compare/select ops.
__global__ __launch_bounds__(256) void softmax_stats_kernel(
    const float* __restrict__ x, float* __restrict__ conf,
    int* __restrict__ pred, int nrows)
{
    const int tid  = threadIdx.x;
    const int wave = tid >> 6;
    const int lane = tid & 63;
    const int rw   = lane >> 4;   // row-within-wave (0..3)
    const int sub  = lane & 15;   // 16 lanes per row
    const long long row = (long long)blockIdx.x * 16 + wave * 4 + rw;
    if (row >= nrows) return;

    const float4 v = ((const float4*)(x + row * C_LEN))[sub];

    // local argmax over 4 elems, strict > keeps lowest index
    float m = v.x; int mi = sub * 4;
    if (v.y > m) { m = v.y; mi = sub * 4 + 1; }
    if (v.z > m) { m = v.z; mi = sub * 4 + 2; }
    if (v.w > m) { m = v.w; mi = sub * 4 + 3; }

    // sign-corrected monotone encoding of float bits
    const unsigned int s0 = __float_as_uint(m);
    const unsigned int u0 = (s0 & 0x80000000u) ? ~s0 : (s0 | 0x80000000u);
    unsigned long long key =
        ((unsigned long long)u0 << 32) | (unsigned int)~mi;

    #pragma unroll
    for (int off = 8; off >= 1; off >>= 1) {
        const unsigned long long o = __shfl_xor(key, off);
        if (o > key) key = o;     // tie in value -> larger ~mi -> smaller mi
    }

    const unsigned int uu = (unsigned int)(key >> 32);
    const float M = __uint_as_float(
        (uu & 0x80000000u) ? (uu ^ 0x80000000u) : ~uu);

    // native exp: v_mul + v_exp_f32 (args are <= 0, no range issues)
    float s = __expf(v.x - M) + __expf(v.y - M)
            + __expf(v.z - M) + __expf(v.w - M);
    #pragma unroll
    for (int off = 8; off >= 1; off >>= 1) s += __shfl_xor(s, off);

    if (sub == 0) {
        conf[row] = 1.0f / s;
        pred[row] = (int)~(unsigned int)(key & 0xffffffffu);
    }
}

// Kernel B: one block per batch sample. RLE + voted-confidence top-8.
// Selection with removal, but: (a) per-wave cached best key, only the wave
// that lost its winner rescans its 2048-elem segment; (b) outputs buffered
// in LDS so no global-store vmcnt drain inside the round loop.
__global__ __launch_bounds__(256) void topk_kernel(
    const float* __restrict__ conf, const int* __restrict__ pred,
    float* __restrict__ out)
{
    __shared__ short pred_s[T_LEN];                 // 16 KB
    __shared__ float voted_s[T_LEN];                // 32 KB
    __shared__ unsigned long long wkey[4];
    __shared__ int   dirty;                         // -1 = all rescan
    __shared__ float outbuf[OUT_LEN];

    const int b    = blockIdx.x;
    const int tid  = threadIdx.x;
    const int lane = tid & 63, wave = tid >> 6;
    const int* __restrict__   pb = pred + (long long)b * T_LEN;
    const float* __restrict__ cb = conf + (long long)b * T_LEN;

    // vectorized pred load: int4 -> 4 shorts
    for (int i = tid; i < T_LEN / 4; i += 256) {
        const int4 p4 = ((const int4*)pb)[i];
        short4 q; q.x = (short)p4.x; q.y = (short)p4.y;
        q.z = (short)p4.z; q.w = (short)p4.w;
        *(short4*)&pred_s[4 * i] = q;
    }
    if (tid == 0) dirty = -1;
    __syncthreads();

    // voted confidence at run starts; 0 elsewhere (real voted >= 1/64 > 0)
    for (int t = tid; t < T_LEN; t += 256) {
        const short p = pred_s[t];
        const bool start = (t == 0) || (pred_s[t - 1] != p);
        float v = 0.0f;
        if (start) {
            int len = 1;
            while (t + len < T_LEN && pred_s[t + len] == p) ++len;
            v = cb[t] * (float)len;   // conf at run START times run length
        }
        voted_s[t] = v;
    }
    __syncthreads();

    // 8 rounds of block argmax over keys (float bits | ~t): float bits are
    // order-preserving for v >= 0; ~t = lower-index tie-break (lax.top_k).
    for (int r = 0; r < OUT_LEN; ++r) {
        if (dirty == -1 || dirty == wave) {
            unsigned long long best = 0ull;
            const int base = wave * (T_LEN / 4);
            #pragma unroll 4
            for (int k = 0; k < T_LEN / 4 / 64; ++k) {
                const int t = base + k * 64 + lane;
                const unsigned long long key =
                    ((unsigned long long)__float_as_uint(voted_s[t]) << 32)
                    | (unsigned int)(~t);
                if (key > best) best = key;
            }
            #pragma unroll
            for (int off = 32; off >= 1; off >>= 1) {
                const unsigned long long o = __shfl_xor(best, off);
                if (o > best) best = o;
            }
            if (lane == 0) wkey[wave] = best;
        }
        __syncthreads();
        if (tid == 0) {
            unsigned long long bb = wkey[0];
            #pragma unroll
            for (int w = 1; w < 4; ++w) if (wkey[w] > bb) bb = wkey[w];
            const unsigned int widx = ~(unsigned int)(bb & 0xffffffffu);
            const float v = __uint_as_float((unsigned int)(bb >> 32));
            float ov = 0.0f;                        // pad-with-0 path
            if (v > 0.0f) {
                ov = (float)pred_s[widx];
                voted_s[widx] = 0.0f;
                dirty = (int)(widx / (T_LEN / 4));  // that wave rescans
            } else {
                dirty = 4;                          // nobody rescans
            }
            outbuf[r] = ov;
        }
        __syncthreads();
    }
    if (tid < OUT_LEN) out[b * OUT_LEN + tid] = outbuf[tid];
}

extern "C" void kernel_launch(void* const* d_in, const int* in_sizes, int n_in,
                              void* d_out, int out_size, void* d_ws, size_t ws_size,
                              hipStream_t stream) {
    const float* x = (const float*)d_in[0];
    const int total = in_sizes[0];          // B*T*C
    const int nrows = total / C_LEN;        // B*T
    const int B     = nrows / T_LEN;

    float* conf = (float*)d_ws;                                        // nrows f32
    int*   pred = (int*)((char*)d_ws + (size_t)nrows * sizeof(float)); // nrows i32
    float* out  = (float*)d_out;

    const int gridA = (nrows + 15) / 16;    // 16 rows per 256-thread block
    // DIAGNOSTIC: kernel A launched twice (idempotent; writes identical
    // values). dur_us = overhead + 2*A + B -> decomposes A vs B vs fixed
    // harness overhead across rounds. Remove once decomposition is known.
    softmax_stats_kernel<<<gridA, 256, 0, stream>>>(x, conf, pred, nrows);
    softmax_stats_kernel<<<gridA, 256, 0, stream>>>(x, conf, pred, nrows);
    topk_kernel<<<B, 256, 0, stream>>>(conf, pred, out);
}